// Round 9
// baseline (733.107 us; speedup 1.0000x reference)
//
#include <hip/hip_runtime.h>
#include <stdint.h>

#define BATCH 16384
#define IN_DIM 1024
#define HDIM 4096

typedef _Float16 f16x8 __attribute__((ext_vector_type(8)));
typedef short short8 __attribute__((ext_vector_type(8)));
typedef float f32x16 __attribute__((ext_vector_type(16)));
typedef int i32x4 __attribute__((ext_vector_type(4)));
typedef int i32x16 __attribute__((ext_vector_type(16)));

typedef const __attribute__((address_space(1))) void* gas_ptr;
typedef __attribute__((address_space(3))) void* las_ptr;

__device__ __forceinline__ void async_copy16(const void* g, void* l) {
  __builtin_amdgcn_global_load_lds((gas_ptr)g, (las_ptr)l, 16, 0, 0);
}

// ---------------- prep kernels (round-6 verified) ----------------

__global__ void cvt_x_f16_kernel(const float* __restrict__ in,
                                 unsigned short* __restrict__ out, int n4) {
  int i = blockIdx.x * blockDim.x + threadIdx.x;
  if (i < n4) {
    const float4 v = ((const float4*)in)[i];
    ushort4 o;
    o.x = __builtin_bit_cast(unsigned short, (_Float16)v.x);
    o.y = __builtin_bit_cast(unsigned short, (_Float16)v.y);
    o.z = __builtin_bit_cast(unsigned short, (_Float16)v.z);
    o.w = __builtin_bit_cast(unsigned short, (_Float16)v.w);
    ((ushort4*)out)[i] = o;
  }
}

__global__ void cvt_s_kernel(const int* __restrict__ s1, unsigned short* __restrict__ o1, int n1_4,
                             const int* __restrict__ s2, unsigned int* __restrict__ o2, int n2_4) {
  int i = blockIdx.x * blockDim.x + threadIdx.x;
  if (i < n1_4) {
    const int4 v = ((const int4*)s1)[i];
    ushort4 o;
    o.x = __builtin_bit_cast(unsigned short, (_Float16)(float)v.x);
    o.y = __builtin_bit_cast(unsigned short, (_Float16)(float)v.y);
    o.z = __builtin_bit_cast(unsigned short, (_Float16)(float)v.z);
    o.w = __builtin_bit_cast(unsigned short, (_Float16)(float)v.w);
    ((ushort4*)o1)[i] = o;
  } else if (i < n1_4 + n2_4) {
    const int j = i - n1_4;
    const int4 v = ((const int4*)s2)[j];
    o2[j] = (v.x & 0xffu) | ((v.y & 0xffu) << 8) | ((v.z & 0xffu) << 16) | ((v.w & 0xffu) << 24);
  }
}

// scale1 = max(softplus,1e-4); scale2 = max(softplus,1e-4)/127 (h1-i8 dequant);
// out[i] = b_out[0] for ALL rows (rounds 4/5 failed on initializing only out[0]).
__global__ void scales_init_kernel(const float* __restrict__ ls1, float* __restrict__ s1,
                                   const float* __restrict__ ls2, float* __restrict__ s2,
                                   const float* __restrict__ b_out, float* __restrict__ out,
                                   int out_n) {
  int i = blockIdx.x * blockDim.x + threadIdx.x;
  if (i < out_n) out[i] = b_out[0];
  if (i < HDIM) {
    float l = ls1[i];
    float sp = (l > 20.0f) ? l : log1pf(expf(l));
    s1[i] = fmaxf(sp, 1e-4f);
  } else if (i < 2 * HDIM) {
    float l = ls2[i - HDIM];
    float sp = (l > 20.0f) ? l : log1pf(expf(l));
    s2[i - HDIM] = fmaxf(sp, 1e-4f) * (1.0f / 127.0f);
  }
}

// ---------------- GEMM1 (f16 MFMA, BK=64) — round-6 verified, unchanged ----

__global__ __launch_bounds__(256, 2)
void gemm1_kernel(const unsigned short* __restrict__ A,
                  const unsigned short* __restrict__ B,
                  const float* __restrict__ scale,
                  const float* __restrict__ bias,
                  signed char* __restrict__ Hout) {
  constexpr int K = IN_DIM;
  __shared__ __align__(16) unsigned short As[256 * 64];  // 32 KB
  __shared__ __align__(16) unsigned short Bs[128 * 64];  // 16 KB

  const int tid = threadIdx.x;
  const int wave = tid >> 6;
  const int lane = tid & 63;
  const int r31 = lane & 31;
  const int half = lane >> 5;
  const int wm = wave >> 1;
  const int wn = wave & 1;
  const int row0 = blockIdx.y * 256;
  const int col0 = blockIdx.x * 128;

  f32x16 acc[4][2];
#pragma unroll
  for (int i = 0; i < 4; ++i)
#pragma unroll
    for (int j = 0; j < 2; ++j)
#pragma unroll
      for (int r = 0; r < 16; ++r) acc[i][j][r] = 0.0f;

  const unsigned short* Ab = A + (size_t)row0 * K;
  const unsigned short* Bb = B + (size_t)col0 * K;

  for (int k0 = 0; k0 < K; k0 += 64) {
    __syncthreads();
#pragma unroll
    for (int rd = 0; rd < 8; ++rd) {
      const int p = rd * 256 + tid;
      const int r = p >> 3;
      const int c = (p & 7) ^ (r & 7);
      async_copy16(Ab + (size_t)r * K + k0 + c * 8, &As[(rd * 256 + wave * 64) * 8]);
    }
#pragma unroll
    for (int rd = 0; rd < 4; ++rd) {
      const int p = rd * 256 + tid;
      const int r = p >> 3;
      const int c = (p & 7) ^ (r & 7);
      async_copy16(Bb + (size_t)r * K + k0 + c * 8, &Bs[(rd * 256 + wave * 64) * 8]);
    }
    __syncthreads();

#pragma unroll
    for (int s = 0; s < 4; ++s) {
      const int c = s * 2 + half;
      f16x8 aF[4], bF[2];
#pragma unroll
      for (int i = 0; i < 4; ++i) {
        const int ar = wm * 128 + i * 32 + r31;
        const int cp = c ^ (ar & 7);
        aF[i] = __builtin_bit_cast(f16x8, *(const short8*)&As[ar * 64 + cp * 8]);
      }
#pragma unroll
      for (int j = 0; j < 2; ++j) {
        const int br = wn * 64 + j * 32 + r31;
        const int cp = c ^ (br & 7);
        bF[j] = __builtin_bit_cast(f16x8, *(const short8*)&Bs[br * 64 + cp * 8]);
      }
#pragma unroll
      for (int i = 0; i < 4; ++i)
#pragma unroll
        for (int j = 0; j < 2; ++j)
          acc[i][j] = __builtin_amdgcn_mfma_f32_32x32x16_f16(aF[i], bF[j], acc[i][j], 0, 0, 0);
    }
  }

#pragma unroll
  for (int j = 0; j < 2; ++j) {
    const int col = col0 + wn * 64 + j * 32 + r31;
    const float sc = scale[col];
    const float bs = bias[col];
#pragma unroll
    for (int i = 0; i < 4; ++i) {
      const int rbase = row0 + wm * 128 + i * 32 + 4 * half;
#pragma unroll
      for (int r = 0; r < 16; ++r) {
        const int row = rbase + (r & 3) + 8 * (r >> 2);
        float v = fminf(fmaxf(acc[i][j][r] * sc + bs, -1.0f), 1.0f);
        Hout[(size_t)row * HDIM + col] = (signed char)(int)rintf(v * 127.0f);
      }
    }
  }
}

// ---------------- GEMM2 (i8 MFMA, BK=128, B direct from global) ----------------
// A: h1_i8 [M][4096] staged via LDS as before (each A byte read by 2 waves).
// B: state2_i8 [4096][4096] loaded DIRECTLY global->VGPR (AITER/flatmm
// pattern) — B's 512 KB working stripe per block-column is L2-resident
// across the 64 row-blocks reusing it. This removes 1/3 of LDS read traffic,
// 1/3 of staged bytes, and 4 of 12 staging rounds. B loads are issued
// between the A-staging copies and the barrier, so their L2 latency hides
// inside the barrier's existing vmcnt(0) drain; compute reads B from regs.
// Per-lane B address (col)*K + k0 + s*32 + half*16: 16B aligned; lane pairs
// cover contiguous 32B per row; s,s+1 share 64B lines.
// Epilogue: fused OUT_DIM=1 head (round-6 verified).

__global__ __launch_bounds__(256, 2)
void gemm2_bd_kernel(const signed char* __restrict__ A,
                     const signed char* __restrict__ B,
                     const float* __restrict__ scale,   // softplus/127
                     const float* __restrict__ bias,
                     const float* __restrict__ w_out,
                     float* __restrict__ out) {
  constexpr int K = HDIM;
  __shared__ __align__(16) signed char As[256 * 128];  // 32 KB (A only)

  const int tid = threadIdx.x;
  const int wave = tid >> 6;
  const int lane = tid & 63;
  const int r31 = lane & 31;
  const int half = lane >> 5;
  const int wm = wave >> 1;
  const int wn = wave & 1;
  const int row0 = blockIdx.y * 256;
  const int col0 = blockIdx.x * 128;

  i32x16 acc[4][2];
#pragma unroll
  for (int i = 0; i < 4; ++i)
#pragma unroll
    for (int j = 0; j < 2; ++j)
#pragma unroll
      for (int r = 0; r < 16; ++r) acc[i][j][r] = 0;

  const signed char* Ab = A + (size_t)row0 * K;
  // per-lane B base: row (col0 + wn*64 + r31), k-offset half*16
  const signed char* Bp = B + (size_t)(col0 + wn * 64 + r31) * K + half * 16;

  for (int k0 = 0; k0 < K; k0 += 128) {
    __syncthreads();
    // A: 256 rows x 128 B = 2048 chunks of 16 B, 8 rounds of 256 lanes.
    // LDS slot p holds global chunk (row=p>>3, chunk=(p&7)^(row&7)).
#pragma unroll
    for (int rd = 0; rd < 8; ++rd) {
      const int p = rd * 256 + tid;
      const int r = p >> 3;
      const int c = (p & 7) ^ (r & 7);
      async_copy16(Ab + (size_t)r * K + k0 + c * 16, &As[(rd * 256 + wave * 64) * 16]);
    }
    // B fragments for this iter: 8 x 16B global->VGPR, latency overlapped
    // with the A-staging drain at the barrier below.
    i32x4 bAll[4][2];
#pragma unroll
    for (int s = 0; s < 4; ++s)
#pragma unroll
      for (int j = 0; j < 2; ++j)
        bAll[s][j] = *(const i32x4*)&Bp[(size_t)j * 32 * K + k0 + s * 32];
    __syncthreads();

    // 4 k-steps of 32: A row = lane&31, k = s*32 + half*16 + j.
#pragma unroll
    for (int s = 0; s < 4; ++s) {
      const int c = s * 2 + half;
      i32x4 aF[4];
#pragma unroll
      for (int i = 0; i < 4; ++i) {
        const int ar = wm * 128 + i * 32 + r31;
        const int cp = c ^ (ar & 7);
        aF[i] = *(const i32x4*)&As[ar * 128 + cp * 16];
      }
#pragma unroll
      for (int i = 0; i < 4; ++i)
#pragma unroll
        for (int j = 0; j < 2; ++j)
          acc[i][j] = __builtin_amdgcn_mfma_i32_32x32x32_i8(aF[i], bAll[s][j], acc[i][j], 0, 0, 0);
    }
  }

  // Fused head: out[row] += sum_col clip(acc*sc+bs)*w_out[col]
  // C/D 32x32 layout: col = lane&31, row = (reg&3)+8*(reg>>2)+4*(lane>>5).
#pragma unroll
  for (int i = 0; i < 4; ++i) {
    float rs[16];
#pragma unroll
    for (int r = 0; r < 16; ++r) rs[r] = 0.0f;
#pragma unroll
    for (int j = 0; j < 2; ++j) {
      const int col = col0 + wn * 64 + j * 32 + r31;
      const float sc = scale[col];
      const float bs = bias[col];
      const float w = w_out[col];
#pragma unroll
      for (int r = 0; r < 16; ++r) {
        float v = fminf(fmaxf((float)acc[i][j][r] * sc + bs, -1.0f), 1.0f);
        rs[r] += v * w;
      }
    }
#pragma unroll
    for (int off = 1; off < 32; off <<= 1)
#pragma unroll
      for (int r = 0; r < 16; ++r)
        rs[r] += __shfl_xor(rs[r], off, 64);
    if (r31 == 0) {
      const int rbase = row0 + wm * 128 + i * 32 + 4 * half;
#pragma unroll
      for (int r = 0; r < 16; ++r)
        atomicAdd(&out[rbase + (r & 3) + 8 * (r >> 2)], rs[r]);
    }
  }
}

// ---------------- launch ----------------

extern "C" void kernel_launch(void* const* d_in, const int* in_sizes, int n_in,
                              void* d_out, int out_size, void* d_ws, size_t ws_size,
                              hipStream_t stream) {
  (void)in_sizes; (void)n_in; (void)ws_size;
  const float* x          = (const float*)d_in[0];
  const int*   state1     = (const int*)d_in[1];
  const float* log_scale1 = (const float*)d_in[2];
  const float* bias1      = (const float*)d_in[3];
  const int*   state2     = (const int*)d_in[4];
  const float* log_scale2 = (const float*)d_in[5];
  const float* bias2      = (const float*)d_in[6];
  const float* w_out      = (const float*)d_in[7];
  const float* b_out      = (const float*)d_in[8];
  float* out = (float*)d_out;

  char* ws = (char*)d_ws;
  unsigned short* xh  = (unsigned short*)ws; ws += (size_t)BATCH * IN_DIM * 2;  // 32 MB
  unsigned short* s1h = (unsigned short*)ws; ws += (size_t)HDIM * IN_DIM * 2;   // 8 MB
  signed char*    s2q = (signed char*)ws;    ws += (size_t)HDIM * HDIM;         // 16 MB
  signed char*    h1q = (signed char*)ws;    ws += (size_t)BATCH * HDIM;        // 64 MB
  float* scale1 = (float*)ws; ws += HDIM * sizeof(float);
  float* scale2 = (float*)ws; ws += HDIM * sizeof(float);

  const int nx4 = BATCH * IN_DIM / 4;
  const int n1_4 = HDIM * IN_DIM / 4;
  const int n2_4 = HDIM * HDIM / 4;

  cvt_x_f16_kernel<<<(nx4 + 255) / 256, 256, 0, stream>>>(x, xh, nx4);
  cvt_s_kernel<<<(n1_4 + n2_4 + 255) / 256, 256, 0, stream>>>(
      state1, s1h, n1_4, state2, (unsigned int*)s2q, n2_4);
  const int init_n = (out_size > 2 * HDIM) ? out_size : 2 * HDIM;
  scales_init_kernel<<<(init_n + 255) / 256, 256, 0, stream>>>(
      log_scale1, scale1, log_scale2, scale2, b_out, out, out_size);

  dim3 grid(HDIM / 128, BATCH / 256);  // 32 x 64
  gemm1_kernel<<<grid, 256, 0, stream>>>(xh, s1h, scale1, bias1, h1q);
  gemm2_bd_kernel<<<grid, 256, 0, stream>>>(h1q, s2q, scale2, bias2, w_out, out);
}

// Round 10
// 617.197 us; speedup vs baseline: 1.1878x; 1.1878x over previous
//
#include <hip/hip_runtime.h>
#include <stdint.h>

#define BATCH 16384
#define IN_DIM 1024
#define HDIM 4096

typedef _Float16 f16x8 __attribute__((ext_vector_type(8)));
typedef short short8 __attribute__((ext_vector_type(8)));
typedef float f32x16 __attribute__((ext_vector_type(16)));
typedef int i32x4 __attribute__((ext_vector_type(4)));
typedef int i32x16 __attribute__((ext_vector_type(16)));

typedef const __attribute__((address_space(1))) void* gas_ptr;
typedef __attribute__((address_space(3))) void* las_ptr;

__device__ __forceinline__ void async_copy16(const void* g, void* l) {
  __builtin_amdgcn_global_load_lds((gas_ptr)g, (las_ptr)l, 16, 0, 0);
}

// ---------------- prep kernels ----------------

// x float -> f16, 4 at a time (x must stay >=16-bit: i8-x measured absmax
// 7.3e-3 > 6.99e-3 threshold in round 7)
__global__ void cvt_x_f16_kernel(const float* __restrict__ in,
                                 unsigned short* __restrict__ out, int n4) {
  int i = blockIdx.x * blockDim.x + threadIdx.x;
  if (i < n4) {
    const float4 v = ((const float4*)in)[i];
    ushort4 o;
    o.x = __builtin_bit_cast(unsigned short, (_Float16)v.x);
    o.y = __builtin_bit_cast(unsigned short, (_Float16)v.y);
    o.z = __builtin_bit_cast(unsigned short, (_Float16)v.z);
    o.w = __builtin_bit_cast(unsigned short, (_Float16)v.w);
    ((ushort4*)out)[i] = o;
  }
}

// state1 -> f16 and state2 -> packed i8 in one launch
__global__ void cvt_s_kernel(const int* __restrict__ s1, unsigned short* __restrict__ o1, int n1_4,
                             const int* __restrict__ s2, unsigned int* __restrict__ o2, int n2_4) {
  int i = blockIdx.x * blockDim.x + threadIdx.x;
  if (i < n1_4) {
    const int4 v = ((const int4*)s1)[i];
    ushort4 o;
    o.x = __builtin_bit_cast(unsigned short, (_Float16)(float)v.x);
    o.y = __builtin_bit_cast(unsigned short, (_Float16)(float)v.y);
    o.z = __builtin_bit_cast(unsigned short, (_Float16)(float)v.z);
    o.w = __builtin_bit_cast(unsigned short, (_Float16)(float)v.w);
    ((ushort4*)o1)[i] = o;
  } else if (i < n1_4 + n2_4) {
    const int j = i - n1_4;
    const int4 v = ((const int4*)s2)[j];
    o2[j] = (v.x & 0xffu) | ((v.y & 0xffu) << 8) | ((v.z & 0xffu) << 16) | ((v.w & 0xffu) << 24);
  }
}

// scale1 = max(softplus,1e-4); scale2 = max(softplus,1e-4)/127 (h1-i8 dequant);
// out[i] = b_out[0] for ALL rows (rounds 4/5 failed on initializing only out[0]).
__global__ void scales_init_kernel(const float* __restrict__ ls1, float* __restrict__ s1,
                                   const float* __restrict__ ls2, float* __restrict__ s2,
                                   const float* __restrict__ b_out, float* __restrict__ out,
                                   int out_n) {
  int i = blockIdx.x * blockDim.x + threadIdx.x;
  if (i < out_n) out[i] = b_out[0];
  if (i < HDIM) {
    float l = ls1[i];
    float sp = (l > 20.0f) ? l : log1pf(expf(l));
    s1[i] = fmaxf(sp, 1e-4f);
  } else if (i < 2 * HDIM) {
    float l = ls2[i - HDIM];
    float sp = (l > 20.0f) ? l : log1pf(expf(l));
    s2[i - HDIM] = fmaxf(sp, 1e-4f) * (1.0f / 127.0f);
  }
}

// ---------------- GEMM1 (f16 MFMA, BK=64): h1_i8 = rint(127*clip(...)) ------
// A: x_f16 [M][1024], B: state1_f16 [4096][1024] (B^T layout).
// 256x128 tile, BK=64 (48 KB LDS/iter), 4 waves (2x2), wave = 128x64 via
// 4x2 mfma_f32_32x32x16_f16, 4 k-steps/iter. LDS: 16B chunk c of row r at
// slot c^(r&7). Epilogue quantizes hardtanh output to i8 for GEMM2.

__global__ __launch_bounds__(256, 2)
void gemm1_kernel(const unsigned short* __restrict__ A,
                  const unsigned short* __restrict__ B,
                  const float* __restrict__ scale,
                  const float* __restrict__ bias,
                  signed char* __restrict__ Hout) {
  constexpr int K = IN_DIM;
  __shared__ __align__(16) unsigned short As[256 * 64];  // 32 KB
  __shared__ __align__(16) unsigned short Bs[128 * 64];  // 16 KB

  const int tid = threadIdx.x;
  const int wave = tid >> 6;
  const int lane = tid & 63;
  const int r31 = lane & 31;
  const int half = lane >> 5;
  const int wm = wave >> 1;
  const int wn = wave & 1;
  const int row0 = blockIdx.y * 256;
  const int col0 = blockIdx.x * 128;

  f32x16 acc[4][2];
#pragma unroll
  for (int i = 0; i < 4; ++i)
#pragma unroll
    for (int j = 0; j < 2; ++j)
#pragma unroll
      for (int r = 0; r < 16; ++r) acc[i][j][r] = 0.0f;

  const unsigned short* Ab = A + (size_t)row0 * K;
  const unsigned short* Bb = B + (size_t)col0 * K;

  for (int k0 = 0; k0 < K; k0 += 64) {
    __syncthreads();
#pragma unroll
    for (int rd = 0; rd < 8; ++rd) {
      const int p = rd * 256 + tid;
      const int r = p >> 3;
      const int c = (p & 7) ^ (r & 7);
      async_copy16(Ab + (size_t)r * K + k0 + c * 8, &As[(rd * 256 + wave * 64) * 8]);
    }
#pragma unroll
    for (int rd = 0; rd < 4; ++rd) {
      const int p = rd * 256 + tid;
      const int r = p >> 3;
      const int c = (p & 7) ^ (r & 7);
      async_copy16(Bb + (size_t)r * K + k0 + c * 8, &Bs[(rd * 256 + wave * 64) * 8]);
    }
    __syncthreads();

#pragma unroll
    for (int s = 0; s < 4; ++s) {
      const int c = s * 2 + half;
      f16x8 aF[4], bF[2];
#pragma unroll
      for (int i = 0; i < 4; ++i) {
        const int ar = wm * 128 + i * 32 + r31;
        const int cp = c ^ (ar & 7);
        aF[i] = __builtin_bit_cast(f16x8, *(const short8*)&As[ar * 64 + cp * 8]);
      }
#pragma unroll
      for (int j = 0; j < 2; ++j) {
        const int br = wn * 64 + j * 32 + r31;
        const int cp = c ^ (br & 7);
        bF[j] = __builtin_bit_cast(f16x8, *(const short8*)&Bs[br * 64 + cp * 8]);
      }
#pragma unroll
      for (int i = 0; i < 4; ++i)
#pragma unroll
        for (int j = 0; j < 2; ++j)
          acc[i][j] = __builtin_amdgcn_mfma_f32_32x32x16_f16(aF[i], bF[j], acc[i][j], 0, 0, 0);
    }
  }

  // C/D 32x32 layout: col = lane&31, row = (reg&3)+8*(reg>>2)+4*(lane>>5)
#pragma unroll
  for (int j = 0; j < 2; ++j) {
    const int col = col0 + wn * 64 + j * 32 + r31;
    const float sc = scale[col];
    const float bs = bias[col];
#pragma unroll
    for (int i = 0; i < 4; ++i) {
      const int rbase = row0 + wm * 128 + i * 32 + 4 * half;
#pragma unroll
      for (int r = 0; r < 16; ++r) {
        const int row = rbase + (r & 3) + 8 * (r >> 2);
        float v = fminf(fmaxf(acc[i][j][r] * sc + bs, -1.0f), 1.0f);
        Hout[(size_t)row * HDIM + col] = (signed char)(int)rintf(v * 127.0f);
      }
    }
  }
}

// ---------------- GEMM2 (i8 MFMA, BK=128, fused head) ----------------
// A: h1_i8 [M][4096], B: state2_i8 [4096][4096] (exact ternary).
// 48 KB LDS stage/iter, mfma_i32_32x32x32_i8, exact i32 accumulation.
// Epilogue fuses the OUT_DIM=1 head. This is the measured optimum of the
// explored space (342 us, MfmaUtil 35%): wave specialization (R8) and
// B-direct-to-VGPR (R9) both regressed ~30% — the vmcnt(0)+barrier drain
// is structural to HIP global_load_lds K-loops; exceeding ~36% of the MFMA
// ceiling requires hipBLASLt-style hand-asm (fine-grained vmcnt), defeated
// at HIP source level per m99-m141/s02.

__global__ __launch_bounds__(256, 2)
void gemm2_kernel(const signed char* __restrict__ A,
                  const signed char* __restrict__ B,
                  const float* __restrict__ scale,   // softplus/127
                  const float* __restrict__ bias,
                  const float* __restrict__ w_out,
                  float* __restrict__ out) {
  constexpr int K = HDIM;
  __shared__ __align__(16) signed char As[256 * 128];  // 32 KB
  __shared__ __align__(16) signed char Bs[128 * 128];  // 16 KB

  const int tid = threadIdx.x;
  const int wave = tid >> 6;
  const int lane = tid & 63;
  const int r31 = lane & 31;
  const int half = lane >> 5;
  const int wm = wave >> 1;
  const int wn = wave & 1;
  const int row0 = blockIdx.y * 256;
  const int col0 = blockIdx.x * 128;

  i32x16 acc[4][2];
#pragma unroll
  for (int i = 0; i < 4; ++i)
#pragma unroll
    for (int j = 0; j < 2; ++j)
#pragma unroll
      for (int r = 0; r < 16; ++r) acc[i][j][r] = 0;

  const signed char* Ab = A + (size_t)row0 * K;
  const signed char* Bb = B + (size_t)col0 * K;

  for (int k0 = 0; k0 < K; k0 += 128) {
    __syncthreads();
#pragma unroll
    for (int rd = 0; rd < 8; ++rd) {
      const int p = rd * 256 + tid;
      const int r = p >> 3;
      const int c = (p & 7) ^ (r & 7);
      async_copy16(Ab + (size_t)r * K + k0 + c * 16, &As[(rd * 256 + wave * 64) * 16]);
    }
#pragma unroll
    for (int rd = 0; rd < 4; ++rd) {
      const int p = rd * 256 + tid;
      const int r = p >> 3;
      const int c = (p & 7) ^ (r & 7);
      async_copy16(Bb + (size_t)r * K + k0 + c * 16, &Bs[(rd * 256 + wave * 64) * 16]);
    }
    __syncthreads();

    // 4 k-steps of 32: row = lane&31, k = s*32 + half*16 + j -> chunk s*2+half
#pragma unroll
    for (int s = 0; s < 4; ++s) {
      const int c = s * 2 + half;
      i32x4 aF[4], bF[2];
#pragma unroll
      for (int i = 0; i < 4; ++i) {
        const int ar = wm * 128 + i * 32 + r31;
        const int cp = c ^ (ar & 7);
        aF[i] = *(const i32x4*)&As[ar * 128 + cp * 16];
      }
#pragma unroll
      for (int j = 0; j < 2; ++j) {
        const int br = wn * 64 + j * 32 + r31;
        const int cp = c ^ (br & 7);
        bF[j] = *(const i32x4*)&Bs[br * 128 + cp * 16];
      }
#pragma unroll
      for (int i = 0; i < 4; ++i)
#pragma unroll
        for (int j = 0; j < 2; ++j)
          acc[i][j] = __builtin_amdgcn_mfma_i32_32x32x32_i8(aF[i], bF[j], acc[i][j], 0, 0, 0);
    }
  }

  // Fused head: out[row] += sum_col clip(acc*sc+bs)*w_out[col]
  // C/D 32x32 layout: col = lane&31, row = (reg&3)+8*(reg>>2)+4*(lane>>5).
#pragma unroll
  for (int i = 0; i < 4; ++i) {
    float rs[16];
#pragma unroll
    for (int r = 0; r < 16; ++r) rs[r] = 0.0f;
#pragma unroll
    for (int j = 0; j < 2; ++j) {
      const int col = col0 + wn * 64 + j * 32 + r31;
      const float sc = scale[col];
      const float bs = bias[col];
      const float w = w_out[col];
#pragma unroll
      for (int r = 0; r < 16; ++r) {
        float v = fminf(fmaxf((float)acc[i][j][r] * sc + bs, -1.0f), 1.0f);
        rs[r] += v * w;
      }
    }
#pragma unroll
    for (int off = 1; off < 32; off <<= 1)
#pragma unroll
      for (int r = 0; r < 16; ++r)
        rs[r] += __shfl_xor(rs[r], off, 64);
    if (r31 == 0) {
      const int rbase = row0 + wm * 128 + i * 32 + 4 * half;
#pragma unroll
      for (int r = 0; r < 16; ++r)
        atomicAdd(&out[rbase + (r & 3) + 8 * (r >> 2)], rs[r]);
    }
  }
}

// ---------------- launch ----------------

extern "C" void kernel_launch(void* const* d_in, const int* in_sizes, int n_in,
                              void* d_out, int out_size, void* d_ws, size_t ws_size,
                              hipStream_t stream) {
  (void)in_sizes; (void)n_in; (void)ws_size;
  const float* x          = (const float*)d_in[0];
  const int*   state1     = (const int*)d_in[1];
  const float* log_scale1 = (const float*)d_in[2];
  const float* bias1      = (const float*)d_in[3];
  const int*   state2     = (const int*)d_in[4];
  const float* log_scale2 = (const float*)d_in[5];
  const float* bias2      = (const float*)d_in[6];
  const float* w_out      = (const float*)d_in[7];
  const float* b_out      = (const float*)d_in[8];
  float* out = (float*)d_out;

  char* ws = (char*)d_ws;
  unsigned short* xh  = (unsigned short*)ws; ws += (size_t)BATCH * IN_DIM * 2;  // 32 MB
  unsigned short* s1h = (unsigned short*)ws; ws += (size_t)HDIM * IN_DIM * 2;   // 8 MB
  signed char*    s2q = (signed char*)ws;    ws += (size_t)HDIM * HDIM;         // 16 MB
  signed char*    h1q = (signed char*)ws;    ws += (size_t)BATCH * HDIM;        // 64 MB
  float* scale1 = (float*)ws; ws += HDIM * sizeof(float);
  float* scale2 = (float*)ws; ws += HDIM * sizeof(float);

  const int nx4 = BATCH * IN_DIM / 4;
  const int n1_4 = HDIM * IN_DIM / 4;
  const int n2_4 = HDIM * HDIM / 4;

  cvt_x_f16_kernel<<<(nx4 + 255) / 256, 256, 0, stream>>>(x, xh, nx4);
  cvt_s_kernel<<<(n1_4 + n2_4 + 255) / 256, 256, 0, stream>>>(
      state1, s1h, n1_4, state2, (unsigned int*)s2q, n2_4);
  const int init_n = (out_size > 2 * HDIM) ? out_size : 2 * HDIM;
  scales_init_kernel<<<(init_n + 255) / 256, 256, 0, stream>>>(
      log_scale1, scale1, log_scale2, scale2, b_out, out, out_size);

  dim3 grid(HDIM / 128, BATCH / 256);  // 32 x 64
  gemm1_kernel<<<grid, 256, 0, stream>>>(xh, s1h, scale1, bias1, h1q);
  gemm2_kernel<<<grid, 256, 0, stream>>>(h1q, s2q, scale2, bias2, w_out, out);
}